// Round 14
// baseline (103.032 us; speedup 1.0000x reference)
//
#include <hip/hip_runtime.h>
#include <math.h>

// ---- problem constants ----
#define B 8
#define NWD 32
#define NHD 32
#define NBOX 1024          // NWD*NHD
#define ZWD 8
#define ZID 32
#define KOBJ 48
#define CFEAT 32
#define WRAW 128
#define HRAW 128
#define CR 28
#define CR2 784
#define FAN 25088          // CFEAT*CR2
#define KB 384             // KOBJ*B

// ---- output offsets (floats, concatenated in reference return order) ----
#define OFF_PROB   0
#define OFF_AREA   8192
#define OFF_CFEW   16384
#define OFF_PFEW   16768
#define OFF_BXF    17152
#define OFF_BYF    17536
#define OFF_BWF    17920
#define OFF_BHF    18304
#define OFF_BMASK  18688
#define OFF_BMASKN 6310144
#define OFF_BIMG   12601600
#define OFF_ZWS    18893056
#define OFF_ZWK    18896128
#define OFF_ZIS    18899200
#define OFF_ZIK    18911488

// ---- workspace offsets (floats) ----
#define WS_SMALL 32768                     // KB*1568 = 602112 floats

// ---- scratch inside big_mask output region (6291456 floats, overwritten later) ----
// part: 49*384*64 = 1204224 | wt: FAN*64 bf16 = 802816 floats | feat_t: 8*128*128*32 = 4194304
// total 6201344 < 6291456  (verified)
#define SCR_PART 0
#define SCR_WT   1204224
#define SCR_FT   2007040

// ---- enc GEMM tiling (v14: channel-minor K, k = pos*32 + c) ----
#define FSPLIT 49          // 49 slices x 16 positions = 784 positions
#define CHK 128            // 4 positions x 32 channels
#define NCH 4
#define MKB 16             // kb rows per block
#define KSTR 152           // LDS row stride in bf16 elems (304B: 16B-aligned)
#define TAPN (MKB*28)      // 448 tap entries per axis

typedef __attribute__((ext_vector_type(8))) short bfrag;    // 8 bf16 (4 VGPRs)
typedef __attribute__((ext_vector_type(4))) float f32x4;

__device__ __forceinline__ float sigm(float x){ return 1.0f/(1.0f+expf(-x)); }
__device__ __forceinline__ float softpl(float x){ return fmaxf(x,0.0f) + log1pf(expf(-fabsf(x))); }
__device__ __forceinline__ float ftanh(float x){
  float t = __expf(2.0f*x);
  return 1.0f - __fdividef(2.0f, t + 1.0f);
}
__device__ __forceinline__ unsigned short f2bf(float f){   // RNE f32->bf16
  unsigned u = __float_as_uint(f);
  unsigned r = u + 0x7FFFu + ((u >> 16) & 1u);
  return (unsigned short)(r >> 16);
}
__device__ __forceinline__ unsigned okey(float f){
  unsigned b = __float_as_uint(f);
  return b ^ ((b & 0x80000000u) ? 0xFFFFFFFFu : 0x80000000u);
}

// K0 (merged): [0,784) wconv (k = pos*32+c order, strided reads);
// [784,1808) feat transpose (b,c,X,Y)->(b,X,Y,c) via LDS pivot;
// [1808,1840) maps + rank top-48 + gather.
__global__ __launch_bounds__(256) void prep_kernel(
    const float* __restrict__ wenc, unsigned short* __restrict__ wt,
    const float* __restrict__ feat, float* __restrict__ featT,
    const float* __restrict__ logit, const float* __restrict__ zmu,
    const float* __restrict__ zstd, const float* __restrict__ zeps,
    const float* __restrict__ wz, const float* __restrict__ bz,
    float* __restrict__ out){
  __shared__ __align__(16) float lsh[32*129];   // transpose tile (padded); maps uses first 1024 as keys
  const int tid = threadIdx.x;
  if (blockIdx.x < 784){
    // fragment for k-step ks (= position): d = t*16+(lane&15), c = (lane>>4)*8 + e
    const int ks = blockIdx.x;
    const int lane = tid & 63;
    const int t = tid >> 6;
    const int d = t*16 + (lane & 15);
    const int c0 = (lane >> 4)*8;
    const float* src = wenc + (size_t)d*FAN + ks;
    unsigned long long p0 = 0ull, p1 = 0ull;
    #pragma unroll
    for (int e = 0; e < 4; e++)
      p0 |= (unsigned long long)f2bf(src[(size_t)(c0+e)*CR2]) << (16*e);
    #pragma unroll
    for (int e = 0; e < 4; e++)
      p1 |= (unsigned long long)f2bf(src[(size_t)(c0+4+e)*CR2]) << (16*e);
    unsigned short* dst = wt + ((size_t)ks*256 + tid)*8;
    *(unsigned long long*)dst       = p0;
    *(unsigned long long*)(dst + 4) = p1;
    return;
  }
  if (blockIdx.x < 1808){
    // transpose: block handles (b, X): feat[b][c][X][Y] -> featT[((b*128+X)*128+Y)*32+c]
    const int bid = blockIdx.x - 784;
    const int b = bid >> 7, X = bid & 127;
    #pragma unroll
    for (int u = 0; u < 16; u++){
      int idx = u*256 + tid;
      int c = idx >> 7, Y = idx & 127;
      lsh[c*129 + Y] = feat[(((size_t)b*CFEAT + c)*WRAW + X)*HRAW + Y];
    }
    __syncthreads();
    float* dstrow = featT + ((size_t)b*16384 + (size_t)X*128)*32;
    #pragma unroll
    for (int u = 0; u < 16; u++){
      int idx = u*256 + tid;
      int Y = idx >> 5, c = idx & 31;
      dstrow[Y*32 + c] = lsh[c*129 + Y];
    }
    return;
  }
  const int bid = blockIdx.x - 1808;
  const int b  = bid >> 2;
  const int sb = bid & 3;
  unsigned* su = (unsigned*)lsh;
  #pragma unroll
  for (int u = 0; u < 4; u++){
    int j = tid + u*256;
    su[j] = okey(logit[b*NBOX + j]);
  }
  const int n = sb*256 + tid;
  const int w = n >> 5, h = n & 31;
  float acc0=bz[0], acc1=bz[1], acc2=bz[2], acc3=bz[3];
  #pragma unroll
  for(int z=0; z<ZWD; z++){
    int id = ((b*ZWD + z)*NWD + w)*NHD + h;
    float s = zmu[id] + zstd[id]*zeps[id];
    acc0 += s*wz[0*ZWD+z]; acc1 += s*wz[1*ZWD+z];
    acc2 += s*wz[2*ZWD+z]; acc3 += s*wz[3*ZWD+z];
  }
  float tx=sigm(acc0), ty=sigm(acc1), tw=sigm(acc2), th=sigm(acc3);
  float bx = (128.0f*((float)w + tx))/32.0f;
  float by = (128.0f*((float)h + ty))/32.0f;
  float bwv = 10.0f + 30.0f*tw;
  float bhv = 10.0f + 30.0f*th;
  float lg = logit[b*NBOX + n];
  out[OFF_PROB + b*NBOX + n] = sigm(lg);
  out[OFF_AREA + b*NBOX + n] = bwv*bhv;
  __syncthreads();
  const unsigned ui = su[n];
  const uint4* su4 = (const uint4*)su;
  int rank = 0;
  #pragma unroll 4
  for (int jq = 0; jq < NBOX/4; jq++){
    uint4 v = su4[jq];
    int j = jq*4;
    rank += (v.x > ui || (v.x == ui && j   < n)) ? 1 : 0;
    rank += (v.y > ui || (v.y == ui && j+1 < n)) ? 1 : 0;
    rank += (v.z > ui || (v.z == ui && j+2 < n)) ? 1 : 0;
    rank += (v.w > ui || (v.w == ui && j+3 < n)) ? 1 : 0;
  }
  if (rank < KOBJ){
    out[OFF_CFEW + rank*B + b] = lg;
    out[OFF_PFEW + rank*B + b] = sigm(lg);
    out[OFF_BXF  + rank*B + b] = bx;
    out[OFF_BYF  + rank*B + b] = by;
    out[OFF_BWF  + rank*B + b] = bwv;
    out[OFF_BHF  + rank*B + b] = bhv;
    #pragma unroll
    for(int z=0; z<ZWD; z++){
      int id = ((b*ZWD + z)*NWD + w)*NHD + h;
      float mu = zmu[id], sd = zstd[id];
      out[OFF_ZWS + (rank*B+b)*ZWD + z] = mu + sd*zeps[id];
      out[OFF_ZWK + (rank*B+b)*ZWD + z] = 0.5f*(mu*mu + sd*sd) - logf(sd) - 0.5f;
    }
  }
}

// K2 (v14): channel-vectorized gather (8x float4 per thread per chunk) + MFMA.
// Thread owns (kb=tid>>4, pos q=(tid>>2)&3, c-group=tid&3): 8 channels of one position.
__global__ __launch_bounds__(256, 4) void enc_kernel(
    const float* __restrict__ featT, const unsigned short* __restrict__ wt,
    const float* __restrict__ outc, float* __restrict__ part){
  __shared__ __align__(16) unsigned short cl0[MKB*KSTR];
  __shared__ __align__(16) unsigned short cl1[MKB*KSTR];
  __shared__ float2 wxs[TAPN]; __shared__ int2 xos[TAPN];
  __shared__ float2 wys[TAPN]; __shared__ int2 yos[TAPN];
  __shared__ float rAx[MKB], rSx[MKB], rAy[MKB], rSy[MKB];
  const int tid = threadIdx.x;
  const int fs  = blockIdx.x % FSPLIT;
  const int kb0 = (blockIdx.x / FSPLIT) * MKB;
  if (tid < MKB){
    float bx = outc[OFF_BXF + kb0 + tid];
    float by = outc[OFF_BYF + kb0 + tid];
    float bw = outc[OFF_BWF + kb0 + tid];
    float bh = outc[OFF_BHF + kb0 + tid];
    float sx = bw * (1.0f/(float)CR), sy = bh * (1.0f/(float)CR);
    rSx[tid] = sx; rSy[tid] = sy;
    rAx[tid] = bx - 0.5f*bw + 0.5f*sx - 0.5f;
    rAy[tid] = by - 0.5f*bh + 0.5f*sy - 0.5f;
  }
  __syncthreads();
  #pragma unroll
  for (int it = 0; it < 4; it++){
    int idx = it*256 + tid;
    if (idx < 2*TAPN){
      int isy = idx >= TAPN;
      int q = idx - (isy ? TAPN : 0);
      int rr = q / 28, i = q - rr*28;
      float A = isy ? rAy[rr] : rAx[rr];
      float S = isy ? rSy[rr] : rSx[rr];
      float x = fmaf((float)i, S, A);
      float x0f = floorf(x); int x0 = (int)x0f;
      float w1 = x - x0f, w0 = 1.0f - w1;
      if ((unsigned)x0     >= WRAW) w0 = 0.f;
      if ((unsigned)(x0+1) >= WRAW) w1 = 0.f;
      int c0 = min(max(x0,0),WRAW-1), c1 = min(max(x0+1,0),WRAW-1);
      if (isy){ wys[q] = make_float2(w0,w1); yos[q] = make_int2(c0, c1); }
      else    { wxs[q] = make_float2(w0,w1); xos[q] = make_int2(c0*HRAW, c1*HRAW); }
    }
  }
  __syncthreads();
  const int grr = tid >> 4;
  const int gpq = (tid >> 2) & 3;
  const int gcg = tid & 3;
  const float* gbase = featT + ((size_t)(grr & (B-1))*16384)*32 + gcg*8;
  const int gkk = gpq*32 + gcg*8;       // chunk-local k offset for this thread's 8 samples
  float4 t00a, t00b, t01a, t01b, t10a, t10b, t11a, t11b;
  float2 gwx, gwy;
  // ---- GATHER(ch): 8 float4 loads (4 taps x 8 channels) ----
  #define GATHER(CH) { \
    int pos = fs*16 + (CH)*4 + gpq; \
    int i = pos / 28, j = pos - i*28; \
    int ii = grr*28 + i, jj = grr*28 + j; \
    gwx = wxs[ii]; gwy = wys[jj]; \
    int2 xo = xos[ii]; int2 yo = yos[jj]; \
    const float* p00 = gbase + (size_t)(xo.x + yo.x)*32; \
    const float* p01 = gbase + (size_t)(xo.x + yo.y)*32; \
    const float* p10 = gbase + (size_t)(xo.y + yo.x)*32; \
    const float* p11 = gbase + (size_t)(xo.y + yo.y)*32; \
    t00a = *(const float4*)p00; t00b = *(const float4*)(p00+4); \
    t01a = *(const float4*)p01; t01b = *(const float4*)(p01+4); \
    t10a = *(const float4*)p10; t10b = *(const float4*)(p10+4); \
    t11a = *(const float4*)p11; t11b = *(const float4*)(p11+4); \
  }
  // ---- STORE(dst): combine 8 samples, one 16B LDS write ----
  #define STORE(DST) { \
    float s[8]; \
    const float* q00 = (const float*)&t00a; const float* q01 = (const float*)&t01a; \
    const float* q10 = (const float*)&t10a; const float* q11 = (const float*)&t11a; \
    _Pragma("unroll") \
    for (int e = 0; e < 4; e++) \
      s[e] = (q00[e]*gwy.x + q01[e]*gwy.y)*gwx.x + (q10[e]*gwy.x + q11[e]*gwy.y)*gwx.y; \
    q00 = (const float*)&t00b; q01 = (const float*)&t01b; \
    q10 = (const float*)&t10b; q11 = (const float*)&t11b; \
    _Pragma("unroll") \
    for (int e = 0; e < 4; e++) \
      s[4+e] = (q00[e]*gwy.x + q01[e]*gwy.y)*gwx.x + (q10[e]*gwy.x + q11[e]*gwy.y)*gwx.y; \
    unsigned long long pk0 = 0ull, pk1 = 0ull; \
    _Pragma("unroll") \
    for (int e = 0; e < 4; e++){ \
      pk0 |= (unsigned long long)f2bf(s[e])   << (16*e); \
      pk1 |= (unsigned long long)f2bf(s[4+e]) << (16*e); \
    } \
    unsigned short* dp = &(DST)[grr*KSTR + gkk]; \
    *(unsigned long long*)dp       = pk0; \
    *(unsigned long long*)(dp + 4) = pk1; \
  }
  GATHER(0);
  STORE(cl0);
  __syncthreads();
  const int lane = tid & 63, wv = tid >> 6;
  const int lr = lane & 15, lg = lane >> 4;
  f32x4 acc = {0.f,0.f,0.f,0.f};
  #pragma unroll
  for (int ch = 0; ch < NCH; ch++){
    unsigned short* cur = (ch & 1) ? cl1 : cl0;
    unsigned short* nxt = (ch & 1) ? cl0 : cl1;
    // B-fragment loads FIRST (oldest in vmcnt FIFO -> MFMA waits only on these)
    const unsigned short* bptr = wt + (size_t)(fs*16 + ch*4)*2048 + wv*512 + lane*8;
    bfrag b0 = *(const bfrag*)(bptr);
    bfrag b1 = *(const bfrag*)(bptr + 2048);
    bfrag b2 = *(const bfrag*)(bptr + 4096);
    bfrag b3 = *(const bfrag*)(bptr + 6144);
    if (ch < NCH-1){ GATHER(ch+1); }           // gathers stay in flight under MFMA
    const unsigned short* arow = &cur[lr*KSTR + lg*8];
    bfrag a0 = *(const bfrag*)(arow);
    bfrag a1 = *(const bfrag*)(arow + 32);
    bfrag a2 = *(const bfrag*)(arow + 64);
    bfrag a3 = *(const bfrag*)(arow + 96);
    acc = __builtin_amdgcn_mfma_f32_16x16x32_bf16(a0, b0, acc, 0, 0, 0);
    acc = __builtin_amdgcn_mfma_f32_16x16x32_bf16(a1, b1, acc, 0, 0, 0);
    acc = __builtin_amdgcn_mfma_f32_16x16x32_bf16(a2, b2, acc, 0, 0, 0);
    acc = __builtin_amdgcn_mfma_f32_16x16x32_bf16(a3, b3, acc, 0, 0, 0);
    if (ch < NCH-1){ STORE(nxt); }
    __syncthreads();
  }
  float* dst = part + ((size_t)fs*KB + kb0)*64;
  #pragma unroll
  for (int r = 0; r < 4; r++){
    int row = lg*4 + r;
    dst[row*64 + wv*16 + lr] = acc[r];
  }
  #undef GATHER
  #undef STORE
}

// K3: reduce enc partials (49 slices) + bias -> zi reparam/KL -> dec GEMM + act -> ws_small
__global__ __launch_bounds__(256) void zi_dec_kernel(
    const float* __restrict__ part, const float* __restrict__ benc,
    const float* __restrict__ ieps, const float* __restrict__ wdec,
    const float* __restrict__ bdec, float* __restrict__ out,
    float* __restrict__ ws){
  int kb = blockIdx.x;
  int d = threadIdx.x & 63, seg = threadIdx.x >> 6;
  float s0=0.f, s1=0.f;
  for (int f = seg; f < FSPLIT; f += 8)
    s0 += part[((size_t)f*KB + kb)*64 + d];
  for (int f = seg+4; f < FSPLIT; f += 8)
    s1 += part[((size_t)f*KB + kb)*64 + d];
  __shared__ float red[4][64];
  __shared__ float zs[ZID];
  __shared__ float cf_s;
  red[seg][d] = s0 + s1;
  __syncthreads();
  if (threadIdx.x < ZID){
    int dd = threadIdx.x;
    float mu = benc[dd]     + red[0][dd]     + red[1][dd]     + red[2][dd]     + red[3][dd];
    float pe = benc[ZID+dd] + red[0][ZID+dd] + red[1][ZID+dd] + red[2][ZID+dd] + red[3][ZID+dd];
    float sd = softpl(pe) + 1e-4f;
    float zsv = mu + sd*ieps[kb*ZID + dd];
    out[OFF_ZIS + kb*ZID + dd] = zsv;
    out[OFF_ZIK + kb*ZID + dd] = 0.5f*(mu*mu + sd*sd) - logf(sd) - 0.5f;
    zs[dd] = zsv;
  }
  if (threadIdx.x == 0) cf_s = out[OFF_CFEW + kb];
  __syncthreads();
  float cf = cf_s;
  for (int f = threadIdx.x; f < 2*CR2; f += 256){
    float a = bdec[f];
    #pragma unroll
    for (int q = 0; q < 8; q++){
      float4 w4 = *(const float4*)&wdec[f*ZID + q*4];
      a = fmaf(zs[q*4+0], w4.x, a);
      a = fmaf(zs[q*4+1], w4.y, a);
      a = fmaf(zs[q*4+2], w4.z, a);
      a = fmaf(zs[q*4+3], w4.w, a);
    }
    float v = (f < CR2) ? softpl(a) : sigm(a);
    ws[WS_SMALL + (size_t)kb*(2*CR2) + f] = v*cf;
  }
}

// K4: fused uncrop + compose with wave-uniform X-range skip.
__global__ __launch_bounds__(256) void uncrop_compose_kernel(
    const float* __restrict__ ws, float* __restrict__ out){
  const int t = blockIdx.x*256 + threadIdx.x;
  const int b = t >> 14, p = t & 16383;
  const int X = p >> 7, Y = p & 127;
  __shared__ float sAx[KOBJ], sSx[KOBJ], sAy[KOBJ], sSy[KOBJ];
  if (threadIdx.x < KOBJ){
    int k = threadIdx.x;
    float bx = out[OFF_BXF + k*B + b], bw = out[OFF_BWF + k*B + b];
    float by = out[OFF_BYF + k*B + b], bh = out[OFF_BHF + k*B + b];
    float ix = __fdividef((float)CR, bw), iy = __fdividef((float)CR, bh);
    sSx[k] = ix; sAx[k] = (0.5f*bw - bx)*ix - 0.5f;
    sSy[k] = iy; sAy[k] = (0.5f*bh - by)*iy - 0.5f;
  }
  __syncthreads();
  const float xc = (float)X + 0.5f, yc = (float)Y + 0.5f;
  float wr[KOBJ];
  float vi[KOBJ];
  float sum = 0.f;
  #pragma unroll
  for (int k = 0; k < KOBJ; k++){
    float x = fmaf(xc, sSx[k], sAx[k]);     // wave-uniform (X uniform per wave)
    float v0 = 0.f, v1 = 0.f;
    if (x > -1.0f && x < (float)CR){        // whole-wave skip when box row-range misses X
      float y = fmaf(yc, sSy[k], sAy[k]);
      const float* sm = ws + WS_SMALL + (size_t)(k*B + b)*(2*CR2);
      float x0f = floorf(x), y0f = floorf(y);
      int x0 = (int)x0f, y0 = (int)y0f;
      float wx1 = x - x0f, wx0 = 1.0f - wx1;
      float wy1 = y - y0f, wy0 = 1.0f - wy1;
      if ((unsigned)x0     >= CR) wx0 = 0.f;
      if ((unsigned)(x0+1) >= CR) wx1 = 0.f;
      if ((unsigned)y0     >= CR) wy0 = 0.f;
      if ((unsigned)(y0+1) >= CR) wy1 = 0.f;
      int x0c = min(max(x0,0),CR-1), x1c = min(max(x0+1,0),CR-1);
      int y0c = min(max(y0,0),CR-1), y1c = min(max(y0+1,0),CR-1);
      const float* r0 = sm + x0c*CR;
      const float* r1 = sm + x1c*CR;
      v0 = (r0[y0c]*wy0 + r0[y1c]*wy1)*wx0 + (r1[y0c]*wy0 + r1[y1c]*wy1)*wx1;
      const float* q0 = r0 + CR2;
      const float* q1 = r1 + CR2;
      v1 = (q0[y0c]*wy0 + q0[y1c]*wy1)*wx0 + (q1[y0c]*wy0 + q1[y1c]*wy1)*wx1;
    }
    wr[k] = v0; vi[k] = v1; sum += v0;
  }
  #pragma unroll
  for (int k = 0; k < KOBJ; k++)
    out[OFF_BIMG + (size_t)(k*B + b)*16384 + p] = vi[k];
  float th = ftanh(sum);
  float inv = 1.0f / fmaxf(sum, 1e-6f);
  #pragma unroll
  for (int k = 0; k < KOBJ; k++){
    size_t o = (size_t)(k*B + b)*16384 + p;
    out[OFF_BMASK  + o] = th * (wr[k] * inv);
    out[OFF_BMASKN + o] = (wr[k] == 0.f) ? 0.f : ftanh(wr[k]);
  }
}

extern "C" void kernel_launch(void* const* d_in, const int* in_sizes, int n_in,
                              void* d_out, int out_size, void* d_ws, size_t ws_size,
                              hipStream_t stream) {
  (void)in_sizes; (void)n_in; (void)out_size; (void)ws_size;
  const float* logit = (const float*)d_in[0];
  const float* zmu   = (const float*)d_in[1];
  const float* zstd  = (const float*)d_in[2];
  const float* zeps  = (const float*)d_in[3];
  const float* ieps  = (const float*)d_in[4];
  const float* feat  = (const float*)d_in[5];
  const float* wz    = (const float*)d_in[6];
  const float* bz    = (const float*)d_in[7];
  const float* wenc  = (const float*)d_in[8];
  const float* benc  = (const float*)d_in[9];
  const float* wdec  = (const float*)d_in[10];
  const float* bdec  = (const float*)d_in[11];
  float* out = (float*)d_out;
  float* ws  = (float*)d_ws;
  float* scr = out + OFF_BMASK;                 // scratch inside big_mask region, overwritten later
  float* part = scr + SCR_PART;                 // 1.2M floats
  unsigned short* wt = (unsigned short*)(scr + SCR_WT);  // 1.6M bf16, position-major k fragments
  float* featT = scr + SCR_FT;                  // 4.19M floats (b,X,Y,c)

  prep_kernel         <<<784 + 1024 + B*4, 256, 0, stream>>>(wenc, wt, feat, featT,
                                                             logit, zmu, zstd, zeps, wz, bz, out);
  enc_kernel          <<<(KB/MKB)*FSPLIT, 256, 0, stream>>>(featT, wt, out, part);
  zi_dec_kernel       <<<KB, 256, 0, stream>>>(part, benc, ieps, wdec, bdec, out, ws);
  uncrop_compose_kernel<<<(B*WRAW*HRAW)/256, 256, 0, stream>>>(ws, out);
}

// Round 15
// 96.880 us; speedup vs baseline: 1.0635x; 1.0635x over previous
//
#include <hip/hip_runtime.h>
#include <math.h>

// ---- problem constants ----
#define B 8
#define NWD 32
#define NHD 32
#define NBOX 1024          // NWD*NHD
#define ZWD 8
#define ZID 32
#define KOBJ 48
#define CFEAT 32
#define WRAW 128
#define HRAW 128
#define CR 28
#define CR2 784
#define FAN 25088          // CFEAT*CR2
#define KB 384             // KOBJ*B

// ---- output offsets (floats, concatenated in reference return order) ----
#define OFF_PROB   0
#define OFF_AREA   8192
#define OFF_CFEW   16384
#define OFF_PFEW   16768
#define OFF_BXF    17152
#define OFF_BYF    17536
#define OFF_BWF    17920
#define OFF_BHF    18304
#define OFF_BMASK  18688
#define OFF_BMASKN 6310144
#define OFF_BIMG   12601600
#define OFF_ZWS    18893056
#define OFF_ZWK    18896128
#define OFF_ZIS    18899200
#define OFF_ZIK    18911488

// ---- workspace offsets (floats) ----
#define WS_SMALL 32768                     // KB*1568 = 602112 floats

// ---- scratch inside big_mask output region (6291456 floats, overwritten later) ----
// part: 49*384*64 = 1204224 | wt: FAN*64 bf16 = 802816 floats | feat_t: 8*128*128*32 = 4194304
// total 6201344 < 6291456  (verified)
#define SCR_PART 0
#define SCR_WT   1204224
#define SCR_FT   2007040

// ---- enc GEMM tiling (v15: channel-minor K, k = pos*32 + c) ----
#define FSPLIT 49          // 49 slices x 16 positions = 784 positions
#define CHK 128            // 4 positions x 32 channels
#define NCH 4
#define MKB 16             // kb rows per block
#define KSTR 152           // LDS row stride in bf16 elems (304B: 16B-aligned)
#define TAPN (MKB*28)      // 448 tap entries per axis

typedef __attribute__((ext_vector_type(8))) short bfrag;    // 8 bf16 (4 VGPRs)
typedef __attribute__((ext_vector_type(4))) float f32x4;

__device__ __forceinline__ float sigm(float x){ return 1.0f/(1.0f+expf(-x)); }
__device__ __forceinline__ float softpl(float x){ return fmaxf(x,0.0f) + log1pf(expf(-fabsf(x))); }
__device__ __forceinline__ float ftanh(float x){
  float t = __expf(2.0f*x);
  return 1.0f - __fdividef(2.0f, t + 1.0f);
}
__device__ __forceinline__ unsigned short f2bf(float f){   // RNE f32->bf16
  unsigned u = __float_as_uint(f);
  unsigned r = u + 0x7FFFu + ((u >> 16) & 1u);
  return (unsigned short)(r >> 16);
}
__device__ __forceinline__ unsigned okey(float f){
  unsigned b = __float_as_uint(f);
  return b ^ ((b & 0x80000000u) ? 0xFFFFFFFFu : 0x80000000u);
}

// K0 (merged): [0,512) wconv via LDS pivot (coalesced reads, 16B frag writes);
// [512,1536) feat transpose (b,c,X,Y)->(b,X,Y,c); [1536,1568) maps+topk.
__global__ __launch_bounds__(256) void prep_kernel(
    const float* __restrict__ wenc, unsigned short* __restrict__ wt,
    const float* __restrict__ feat, float* __restrict__ featT,
    const float* __restrict__ logit, const float* __restrict__ zmu,
    const float* __restrict__ zstd, const float* __restrict__ zeps,
    const float* __restrict__ wz, const float* __restrict__ bz,
    float* __restrict__ out){
  __shared__ __align__(16) float lsh[32*129];   // pivot tile; maps uses first 1024 as keys
  const int tid = threadIdx.x;
  if (blockIdx.x < 512){
    // wconv: block = (d = bid>>3, pos-tile pt = bid&7 of 98 positions)
    const int d = blockIdx.x >> 3;
    const int pos0 = (blockIdx.x & 7) * 98;
    const float* srcrow = wenc + (size_t)d*FAN + pos0;
    #pragma unroll
    for (int it = 0; it < 13; it++){
      int idx = it*256 + tid;
      if (idx < 32*98){
        int c = idx / 98, pp = idx - c*98;
        lsh[c*101 + pp] = srcrow[(size_t)c*CR2 + pp];
      }
    }
    __syncthreads();
    const int t = d >> 4, dl = d & 15;
    #pragma unroll
    for (int it = 0; it < 2; it++){
      int idx = it*256 + tid;
      if (idx < 98*4){
        int pos_l = idx >> 2, cg = idx & 3;
        unsigned long long pk0 = 0ull, pk1 = 0ull;
        #pragma unroll
        for (int e = 0; e < 4; e++)
          pk0 |= (unsigned long long)f2bf(lsh[(cg*8+e)*101 + pos_l]) << (16*e);
        #pragma unroll
        for (int e = 0; e < 4; e++)
          pk1 |= (unsigned long long)f2bf(lsh[(cg*8+4+e)*101 + pos_l]) << (16*e);
        unsigned short* dst = wt + (size_t)(pos0+pos_l)*2048 + t*512 + (dl + cg*16)*8;
        *(unsigned long long*)dst       = pk0;
        *(unsigned long long*)(dst + 4) = pk1;
      }
    }
    return;
  }
  if (blockIdx.x < 1536){
    // transpose: block = (b, X): feat[b][c][X][Y] -> featT[((b*128+X)*128+Y)*32+c]
    const int bid = blockIdx.x - 512;
    const int b = bid >> 7, X = bid & 127;
    #pragma unroll
    for (int u = 0; u < 16; u++){
      int idx = u*256 + tid;
      int c = idx >> 7, Y = idx & 127;
      lsh[c*129 + Y] = feat[(((size_t)b*CFEAT + c)*WRAW + X)*HRAW + Y];
    }
    __syncthreads();
    float* dstrow = featT + ((size_t)b*16384 + (size_t)X*128)*32;
    #pragma unroll
    for (int u = 0; u < 16; u++){
      int idx = u*256 + tid;
      int Y = idx >> 5, c = idx & 31;
      dstrow[Y*32 + c] = lsh[c*129 + Y];
    }
    return;
  }
  const int bid = blockIdx.x - 1536;
  const int b  = bid >> 2;
  const int sb = bid & 3;
  unsigned* su = (unsigned*)lsh;
  #pragma unroll
  for (int u = 0; u < 4; u++){
    int j = tid + u*256;
    su[j] = okey(logit[b*NBOX + j]);
  }
  const int n = sb*256 + tid;
  const int w = n >> 5, h = n & 31;
  float acc0=bz[0], acc1=bz[1], acc2=bz[2], acc3=bz[3];
  #pragma unroll
  for(int z=0; z<ZWD; z++){
    int id = ((b*ZWD + z)*NWD + w)*NHD + h;
    float s = zmu[id] + zstd[id]*zeps[id];
    acc0 += s*wz[0*ZWD+z]; acc1 += s*wz[1*ZWD+z];
    acc2 += s*wz[2*ZWD+z]; acc3 += s*wz[3*ZWD+z];
  }
  float tx=sigm(acc0), ty=sigm(acc1), tw=sigm(acc2), th=sigm(acc3);
  float bx = (128.0f*((float)w + tx))/32.0f;
  float by = (128.0f*((float)h + ty))/32.0f;
  float bwv = 10.0f + 30.0f*tw;
  float bhv = 10.0f + 30.0f*th;
  float lg = logit[b*NBOX + n];
  out[OFF_PROB + b*NBOX + n] = sigm(lg);
  out[OFF_AREA + b*NBOX + n] = bwv*bhv;
  __syncthreads();
  const unsigned ui = su[n];
  const uint4* su4 = (const uint4*)su;
  int rank = 0;
  #pragma unroll 4
  for (int jq = 0; jq < NBOX/4; jq++){
    uint4 v = su4[jq];
    int j = jq*4;
    rank += (v.x > ui || (v.x == ui && j   < n)) ? 1 : 0;
    rank += (v.y > ui || (v.y == ui && j+1 < n)) ? 1 : 0;
    rank += (v.z > ui || (v.z == ui && j+2 < n)) ? 1 : 0;
    rank += (v.w > ui || (v.w == ui && j+3 < n)) ? 1 : 0;
  }
  if (rank < KOBJ){
    out[OFF_CFEW + rank*B + b] = lg;
    out[OFF_PFEW + rank*B + b] = sigm(lg);
    out[OFF_BXF  + rank*B + b] = bx;
    out[OFF_BYF  + rank*B + b] = by;
    out[OFF_BWF  + rank*B + b] = bwv;
    out[OFF_BHF  + rank*B + b] = bhv;
    #pragma unroll
    for(int z=0; z<ZWD; z++){
      int id = ((b*ZWD + z)*NWD + w)*NHD + h;
      float mu = zmu[id], sd = zstd[id];
      out[OFF_ZWS + (rank*B+b)*ZWD + z] = mu + sd*zeps[id];
      out[OFF_ZWK + (rank*B+b)*ZWD + z] = 0.5f*(mu*mu + sd*sd) - logf(sd) - 0.5f;
    }
  }
}

// K2 (v14): channel-vectorized gather (8x float4 per thread per chunk) + MFMA.
__global__ __launch_bounds__(256, 4) void enc_kernel(
    const float* __restrict__ featT, const unsigned short* __restrict__ wt,
    const float* __restrict__ outc, float* __restrict__ part){
  __shared__ __align__(16) unsigned short cl0[MKB*KSTR];
  __shared__ __align__(16) unsigned short cl1[MKB*KSTR];
  __shared__ float2 wxs[TAPN]; __shared__ int2 xos[TAPN];
  __shared__ float2 wys[TAPN]; __shared__ int2 yos[TAPN];
  __shared__ float rAx[MKB], rSx[MKB], rAy[MKB], rSy[MKB];
  const int tid = threadIdx.x;
  const int fs  = blockIdx.x % FSPLIT;
  const int kb0 = (blockIdx.x / FSPLIT) * MKB;
  if (tid < MKB){
    float bx = outc[OFF_BXF + kb0 + tid];
    float by = outc[OFF_BYF + kb0 + tid];
    float bw = outc[OFF_BWF + kb0 + tid];
    float bh = outc[OFF_BHF + kb0 + tid];
    float sx = bw * (1.0f/(float)CR), sy = bh * (1.0f/(float)CR);
    rSx[tid] = sx; rSy[tid] = sy;
    rAx[tid] = bx - 0.5f*bw + 0.5f*sx - 0.5f;
    rAy[tid] = by - 0.5f*bh + 0.5f*sy - 0.5f;
  }
  __syncthreads();
  #pragma unroll
  for (int it = 0; it < 4; it++){
    int idx = it*256 + tid;
    if (idx < 2*TAPN){
      int isy = idx >= TAPN;
      int q = idx - (isy ? TAPN : 0);
      int rr = q / 28, i = q - rr*28;
      float A = isy ? rAy[rr] : rAx[rr];
      float S = isy ? rSy[rr] : rSx[rr];
      float x = fmaf((float)i, S, A);
      float x0f = floorf(x); int x0 = (int)x0f;
      float w1 = x - x0f, w0 = 1.0f - w1;
      if ((unsigned)x0     >= WRAW) w0 = 0.f;
      if ((unsigned)(x0+1) >= WRAW) w1 = 0.f;
      int c0 = min(max(x0,0),WRAW-1), c1 = min(max(x0+1,0),WRAW-1);
      if (isy){ wys[q] = make_float2(w0,w1); yos[q] = make_int2(c0, c1); }
      else    { wxs[q] = make_float2(w0,w1); xos[q] = make_int2(c0*HRAW, c1*HRAW); }
    }
  }
  __syncthreads();
  const int grr = tid >> 4;
  const int gpq = (tid >> 2) & 3;
  const int gcg = tid & 3;
  const float* gbase = featT + ((size_t)(grr & (B-1))*16384)*32 + gcg*8;
  const int gkk = gpq*32 + gcg*8;
  float4 t00a, t00b, t01a, t01b, t10a, t10b, t11a, t11b;
  float2 gwx, gwy;
  #define GATHER(CH) { \
    int pos = fs*16 + (CH)*4 + gpq; \
    int i = pos / 28, j = pos - i*28; \
    int ii = grr*28 + i, jj = grr*28 + j; \
    gwx = wxs[ii]; gwy = wys[jj]; \
    int2 xo = xos[ii]; int2 yo = yos[jj]; \
    const float* p00 = gbase + (size_t)(xo.x + yo.x)*32; \
    const float* p01 = gbase + (size_t)(xo.x + yo.y)*32; \
    const float* p10 = gbase + (size_t)(xo.y + yo.x)*32; \
    const float* p11 = gbase + (size_t)(xo.y + yo.y)*32; \
    t00a = *(const float4*)p00; t00b = *(const float4*)(p00+4); \
    t01a = *(const float4*)p01; t01b = *(const float4*)(p01+4); \
    t10a = *(const float4*)p10; t10b = *(const float4*)(p10+4); \
    t11a = *(const float4*)p11; t11b = *(const float4*)(p11+4); \
  }
  #define STORE(DST) { \
    float s[8]; \
    const float* q00 = (const float*)&t00a; const float* q01 = (const float*)&t01a; \
    const float* q10 = (const float*)&t10a; const float* q11 = (const float*)&t11a; \
    _Pragma("unroll") \
    for (int e = 0; e < 4; e++) \
      s[e] = (q00[e]*gwy.x + q01[e]*gwy.y)*gwx.x + (q10[e]*gwy.x + q11[e]*gwy.y)*gwx.y; \
    q00 = (const float*)&t00b; q01 = (const float*)&t01b; \
    q10 = (const float*)&t10b; q11 = (const float*)&t11b; \
    _Pragma("unroll") \
    for (int e = 0; e < 4; e++) \
      s[4+e] = (q00[e]*gwy.x + q01[e]*gwy.y)*gwx.x + (q10[e]*gwy.x + q11[e]*gwy.y)*gwx.y; \
    unsigned long long pk0 = 0ull, pk1 = 0ull; \
    _Pragma("unroll") \
    for (int e = 0; e < 4; e++){ \
      pk0 |= (unsigned long long)f2bf(s[e])   << (16*e); \
      pk1 |= (unsigned long long)f2bf(s[4+e]) << (16*e); \
    } \
    unsigned short* dp = &(DST)[grr*KSTR + gkk]; \
    *(unsigned long long*)dp       = pk0; \
    *(unsigned long long*)(dp + 4) = pk1; \
  }
  GATHER(0);
  STORE(cl0);
  __syncthreads();
  const int lane = tid & 63, wv = tid >> 6;
  const int lr = lane & 15, lg = lane >> 4;
  f32x4 acc = {0.f,0.f,0.f,0.f};
  #pragma unroll
  for (int ch = 0; ch < NCH; ch++){
    unsigned short* cur = (ch & 1) ? cl1 : cl0;
    unsigned short* nxt = (ch & 1) ? cl0 : cl1;
    const unsigned short* bptr = wt + (size_t)(fs*16 + ch*4)*2048 + wv*512 + lane*8;
    bfrag b0 = *(const bfrag*)(bptr);
    bfrag b1 = *(const bfrag*)(bptr + 2048);
    bfrag b2 = *(const bfrag*)(bptr + 4096);
    bfrag b3 = *(const bfrag*)(bptr + 6144);
    if (ch < NCH-1){ GATHER(ch+1); }           // gathers stay in flight under MFMA
    const unsigned short* arow = &cur[lr*KSTR + lg*8];
    bfrag a0 = *(const bfrag*)(arow);
    bfrag a1 = *(const bfrag*)(arow + 32);
    bfrag a2 = *(const bfrag*)(arow + 64);
    bfrag a3 = *(const bfrag*)(arow + 96);
    acc = __builtin_amdgcn_mfma_f32_16x16x32_bf16(a0, b0, acc, 0, 0, 0);
    acc = __builtin_amdgcn_mfma_f32_16x16x32_bf16(a1, b1, acc, 0, 0, 0);
    acc = __builtin_amdgcn_mfma_f32_16x16x32_bf16(a2, b2, acc, 0, 0, 0);
    acc = __builtin_amdgcn_mfma_f32_16x16x32_bf16(a3, b3, acc, 0, 0, 0);
    if (ch < NCH-1){ STORE(nxt); }
    __syncthreads();
  }
  float* dst = part + ((size_t)fs*KB + kb0)*64;
  #pragma unroll
  for (int r = 0; r < 4; r++){
    int row = lg*4 + r;
    dst[row*64 + wv*16 + lr] = acc[r];
  }
  #undef GATHER
  #undef STORE
}

// K3: reduce enc partials (49 slices) + bias -> zi reparam/KL -> dec GEMM + act -> ws_small
__global__ __launch_bounds__(256) void zi_dec_kernel(
    const float* __restrict__ part, const float* __restrict__ benc,
    const float* __restrict__ ieps, const float* __restrict__ wdec,
    const float* __restrict__ bdec, float* __restrict__ out,
    float* __restrict__ ws){
  int kb = blockIdx.x;
  int d = threadIdx.x & 63, seg = threadIdx.x >> 6;
  float s0=0.f, s1=0.f;
  for (int f = seg; f < FSPLIT; f += 8)
    s0 += part[((size_t)f*KB + kb)*64 + d];
  for (int f = seg+4; f < FSPLIT; f += 8)
    s1 += part[((size_t)f*KB + kb)*64 + d];
  __shared__ float red[4][64];
  __shared__ float zs[ZID];
  __shared__ float cf_s;
  red[seg][d] = s0 + s1;
  __syncthreads();
  if (threadIdx.x < ZID){
    int dd = threadIdx.x;
    float mu = benc[dd]     + red[0][dd]     + red[1][dd]     + red[2][dd]     + red[3][dd];
    float pe = benc[ZID+dd] + red[0][ZID+dd] + red[1][ZID+dd] + red[2][ZID+dd] + red[3][ZID+dd];
    float sd = softpl(pe) + 1e-4f;
    float zsv = mu + sd*ieps[kb*ZID + dd];
    out[OFF_ZIS + kb*ZID + dd] = zsv;
    out[OFF_ZIK + kb*ZID + dd] = 0.5f*(mu*mu + sd*sd) - logf(sd) - 0.5f;
    zs[dd] = zsv;
  }
  if (threadIdx.x == 0) cf_s = out[OFF_CFEW + kb];
  __syncthreads();
  float cf = cf_s;
  for (int f = threadIdx.x; f < 2*CR2; f += 256){
    float a = bdec[f];
    #pragma unroll
    for (int q = 0; q < 8; q++){
      float4 w4 = *(const float4*)&wdec[f*ZID + q*4];
      a = fmaf(zs[q*4+0], w4.x, a);
      a = fmaf(zs[q*4+1], w4.y, a);
      a = fmaf(zs[q*4+2], w4.z, a);
      a = fmaf(zs[q*4+3], w4.w, a);
    }
    float v = (f < CR2) ? softpl(a) : sigm(a);
    ws[WS_SMALL + (size_t)kb*(2*CR2) + f] = v*cf;
  }
}

// K4: fused uncrop + compose with wave-uniform X-range skip.
__global__ __launch_bounds__(256) void uncrop_compose_kernel(
    const float* __restrict__ ws, float* __restrict__ out){
  const int t = blockIdx.x*256 + threadIdx.x;
  const int b = t >> 14, p = t & 16383;
  const int X = p >> 7, Y = p & 127;
  __shared__ float sAx[KOBJ], sSx[KOBJ], sAy[KOBJ], sSy[KOBJ];
  if (threadIdx.x < KOBJ){
    int k = threadIdx.x;
    float bx = out[OFF_BXF + k*B + b], bw = out[OFF_BWF + k*B + b];
    float by = out[OFF_BYF + k*B + b], bh = out[OFF_BHF + k*B + b];
    float ix = __fdividef((float)CR, bw), iy = __fdividef((float)CR, bh);
    sSx[k] = ix; sAx[k] = (0.5f*bw - bx)*ix - 0.5f;
    sSy[k] = iy; sAy[k] = (0.5f*bh - by)*iy - 0.5f;
  }
  __syncthreads();
  const float xc = (float)X + 0.5f, yc = (float)Y + 0.5f;
  float wr[KOBJ];
  float vi[KOBJ];
  float sum = 0.f;
  #pragma unroll
  for (int k = 0; k < KOBJ; k++){
    float x = fmaf(xc, sSx[k], sAx[k]);     // wave-uniform (X uniform per wave)
    float v0 = 0.f, v1 = 0.f;
    if (x > -1.0f && x < (float)CR){        // whole-wave skip when box row-range misses X
      float y = fmaf(yc, sSy[k], sAy[k]);
      const float* sm = ws + WS_SMALL + (size_t)(k*B + b)*(2*CR2);
      float x0f = floorf(x), y0f = floorf(y);
      int x0 = (int)x0f, y0 = (int)y0f;
      float wx1 = x - x0f, wx0 = 1.0f - wx1;
      float wy1 = y - y0f, wy0 = 1.0f - wy1;
      if ((unsigned)x0     >= CR) wx0 = 0.f;
      if ((unsigned)(x0+1) >= CR) wx1 = 0.f;
      if ((unsigned)y0     >= CR) wy0 = 0.f;
      if ((unsigned)(y0+1) >= CR) wy1 = 0.f;
      int x0c = min(max(x0,0),CR-1), x1c = min(max(x0+1,0),CR-1);
      int y0c = min(max(y0,0),CR-1), y1c = min(max(y0+1,0),CR-1);
      const float* r0 = sm + x0c*CR;
      const float* r1 = sm + x1c*CR;
      v0 = (r0[y0c]*wy0 + r0[y1c]*wy1)*wx0 + (r1[y0c]*wy0 + r1[y1c]*wy1)*wx1;
      const float* q0 = r0 + CR2;
      const float* q1 = r1 + CR2;
      v1 = (q0[y0c]*wy0 + q0[y1c]*wy1)*wx0 + (q1[y0c]*wy0 + q1[y1c]*wy1)*wx1;
    }
    wr[k] = v0; vi[k] = v1; sum += v0;
  }
  #pragma unroll
  for (int k = 0; k < KOBJ; k++)
    out[OFF_BIMG + (size_t)(k*B + b)*16384 + p] = vi[k];
  float th = ftanh(sum);
  float inv = 1.0f / fmaxf(sum, 1e-6f);
  #pragma unroll
  for (int k = 0; k < KOBJ; k++){
    size_t o = (size_t)(k*B + b)*16384 + p;
    out[OFF_BMASK  + o] = th * (wr[k] * inv);
    out[OFF_BMASKN + o] = (wr[k] == 0.f) ? 0.f : ftanh(wr[k]);
  }
}

extern "C" void kernel_launch(void* const* d_in, const int* in_sizes, int n_in,
                              void* d_out, int out_size, void* d_ws, size_t ws_size,
                              hipStream_t stream) {
  (void)in_sizes; (void)n_in; (void)out_size; (void)ws_size;
  const float* logit = (const float*)d_in[0];
  const float* zmu   = (const float*)d_in[1];
  const float* zstd  = (const float*)d_in[2];
  const float* zeps  = (const float*)d_in[3];
  const float* ieps  = (const float*)d_in[4];
  const float* feat  = (const float*)d_in[5];
  const float* wz    = (const float*)d_in[6];
  const float* bz    = (const float*)d_in[7];
  const float* wenc  = (const float*)d_in[8];
  const float* benc  = (const float*)d_in[9];
  const float* wdec  = (const float*)d_in[10];
  const float* bdec  = (const float*)d_in[11];
  float* out = (float*)d_out;
  float* ws  = (float*)d_ws;
  float* scr = out + OFF_BMASK;                 // scratch inside big_mask region, overwritten later
  float* part = scr + SCR_PART;                 // 1.2M floats
  unsigned short* wt = (unsigned short*)(scr + SCR_WT);  // 1.6M bf16, position-major k fragments
  float* featT = scr + SCR_FT;                  // 4.19M floats (b,X,Y,c)

  prep_kernel         <<<512 + 1024 + B*4, 256, 0, stream>>>(wenc, wt, feat, featT,
                                                             logit, zmu, zstd, zeps, wz, bz, out);
  enc_kernel          <<<(KB/MKB)*FSPLIT, 256, 0, stream>>>(featT, wt, out, part);
  zi_dec_kernel       <<<KB, 256, 0, stream>>>(part, benc, ieps, wdec, bdec, out, ws);
  uncrop_compose_kernel<<<(B*WRAW*HRAW)/256, 256, 0, stream>>>(ws, out);
}

// Round 16
// 91.606 us; speedup vs baseline: 1.1247x; 1.0576x over previous
//
#include <hip/hip_runtime.h>
#include <math.h>

// ---- problem constants ----
#define B 8
#define NWD 32
#define NHD 32
#define NBOX 1024          // NWD*NHD
#define ZWD 8
#define ZID 32
#define KOBJ 48
#define CFEAT 32
#define WRAW 128
#define HRAW 128
#define CR 28
#define CR2 784
#define FAN 25088          // CFEAT*CR2
#define KB 384             // KOBJ*B

// ---- output offsets (floats, concatenated in reference return order) ----
#define OFF_PROB   0
#define OFF_AREA   8192
#define OFF_CFEW   16384
#define OFF_PFEW   16768
#define OFF_BXF    17152
#define OFF_BYF    17536
#define OFF_BWF    17920
#define OFF_BHF    18304
#define OFF_BMASK  18688
#define OFF_BMASKN 6310144
#define OFF_BIMG   12601600
#define OFF_ZWS    18893056
#define OFF_ZWK    18896128
#define OFF_ZIS    18899200
#define OFF_ZIK    18911488

// ---- workspace offsets (floats) ----
#define WS_SMALL 32768                     // KB*1568 = 602112 floats

// ---- scratch inside big_mask output region (6291456 floats, overwritten later) ----
#define SCR_PART 0                         // 49*384*64 = 1204224 floats
#define SCR_WT   1204224                   // FAN*64 bf16 = 802816 floats; ends 2007040 < 6291456

// ---- enc GEMM tiling (v13: async-split gather, CHK=128, FSPLIT=49) ----
#define FSPLIT 49
#define FPB 512            // K per block = 4 chunks x 128
#define CHK 128
#define NCH 4
#define MKB 16             // kb rows per block
#define KSTR 152           // LDS row stride in bf16 elems (304B: 16B-aligned)
#define TAPN (MKB*28)      // 448 tap entries per axis

typedef __attribute__((ext_vector_type(8))) short bfrag;    // 8 bf16 (4 VGPRs)
typedef __attribute__((ext_vector_type(4))) float f32x4;

__device__ __forceinline__ float sigm(float x){ return 1.0f/(1.0f+expf(-x)); }
__device__ __forceinline__ float softpl(float x){ return fmaxf(x,0.0f) + log1pf(expf(-fabsf(x))); }
__device__ __forceinline__ float ftanh(float x){
  float t = __expf(2.0f*x);
  return 1.0f - __fdividef(2.0f, t + 1.0f);
}
__device__ __forceinline__ unsigned short f2bf(float f){   // RNE f32->bf16
  unsigned u = __float_as_uint(f);
  unsigned r = u + 0x7FFFu + ((u >> 16) & 1u);
  return (unsigned short)(r >> 16);
}
__device__ __forceinline__ unsigned okey(float f){
  unsigned b = __float_as_uint(f);
  return b ^ ((b & 0x80000000u) ? 0xFFFFFFFFu : 0x80000000u);
}

// K0 (merged): blocks [0,784) = wconv (one block per global k-step ks);
// blocks [784,816) = maps + rank top-48 + gather.
__global__ __launch_bounds__(256) void prep_kernel(
    const float* __restrict__ wenc, unsigned short* __restrict__ wt,
    const float* __restrict__ logit, const float* __restrict__ zmu,
    const float* __restrict__ zstd, const float* __restrict__ zeps,
    const float* __restrict__ wz, const float* __restrict__ bz,
    float* __restrict__ out){
  __shared__ __align__(16) unsigned su[NBOX];
  if (blockIdx.x < 784){
    const int ks = blockIdx.x;
    const int tid = threadIdx.x;
    const int lane = tid & 63;
    const int t = tid >> 6;
    const int d = t*16 + (lane & 15);
    const int k0 = ks*32 + (lane >> 4)*8;
    const float* src = wenc + (size_t)d*FAN + k0;
    float4 a = *(const float4*)src;
    float4 b = *(const float4*)(src + 4);
    unsigned long long p0 = (unsigned long long)f2bf(a.x)
      | ((unsigned long long)f2bf(a.y) << 16)
      | ((unsigned long long)f2bf(a.z) << 32)
      | ((unsigned long long)f2bf(a.w) << 48);
    unsigned long long p1 = (unsigned long long)f2bf(b.x)
      | ((unsigned long long)f2bf(b.y) << 16)
      | ((unsigned long long)f2bf(b.z) << 32)
      | ((unsigned long long)f2bf(b.w) << 48);
    unsigned short* dst = wt + ((size_t)ks*256 + tid)*8;
    *(unsigned long long*)dst       = p0;
    *(unsigned long long*)(dst + 4) = p1;
    return;
  }
  const int bid = blockIdx.x - 784;
  const int b  = bid >> 2;
  const int sb = bid & 3;
  const int tid = threadIdx.x;
  #pragma unroll
  for (int u = 0; u < 4; u++){
    int j = tid + u*256;
    su[j] = okey(logit[b*NBOX + j]);
  }
  const int n = sb*256 + tid;
  const int w = n >> 5, h = n & 31;
  float acc0=bz[0], acc1=bz[1], acc2=bz[2], acc3=bz[3];
  #pragma unroll
  for(int z=0; z<ZWD; z++){
    int id = ((b*ZWD + z)*NWD + w)*NHD + h;
    float s = zmu[id] + zstd[id]*zeps[id];
    acc0 += s*wz[0*ZWD+z]; acc1 += s*wz[1*ZWD+z];
    acc2 += s*wz[2*ZWD+z]; acc3 += s*wz[3*ZWD+z];
  }
  float tx=sigm(acc0), ty=sigm(acc1), tw=sigm(acc2), th=sigm(acc3);
  float bx = (128.0f*((float)w + tx))/32.0f;
  float by = (128.0f*((float)h + ty))/32.0f;
  float bwv = 10.0f + 30.0f*tw;
  float bhv = 10.0f + 30.0f*th;
  float lg = logit[b*NBOX + n];
  out[OFF_PROB + b*NBOX + n] = sigm(lg);
  out[OFF_AREA + b*NBOX + n] = bwv*bhv;
  __syncthreads();
  const unsigned ui = su[n];
  const uint4* su4 = (const uint4*)su;
  int rank = 0;
  #pragma unroll 4
  for (int jq = 0; jq < NBOX/4; jq++){
    uint4 v = su4[jq];
    int j = jq*4;
    rank += (v.x > ui || (v.x == ui && j   < n)) ? 1 : 0;
    rank += (v.y > ui || (v.y == ui && j+1 < n)) ? 1 : 0;
    rank += (v.z > ui || (v.z == ui && j+2 < n)) ? 1 : 0;
    rank += (v.w > ui || (v.w == ui && j+3 < n)) ? 1 : 0;
  }
  if (rank < KOBJ){
    out[OFF_CFEW + rank*B + b] = lg;
    out[OFF_PFEW + rank*B + b] = sigm(lg);
    out[OFF_BXF  + rank*B + b] = bx;
    out[OFF_BYF  + rank*B + b] = by;
    out[OFF_BWF  + rank*B + b] = bwv;
    out[OFF_BHF  + rank*B + b] = bhv;
    #pragma unroll
    for(int z=0; z<ZWD; z++){
      int id = ((b*ZWD + z)*NWD + w)*NHD + h;
      float mu = zmu[id], sd = zstd[id];
      out[OFF_ZWS + (rank*B+b)*ZWD + z] = mu + sd*zeps[id];
      out[OFF_ZWK + (rank*B+b)*ZWD + z] = 0.5f*(mu*mu + sd*sd) - logf(sd) - 0.5f;
    }
  }
}

// K2 (v13): async-split crop gather + MFMA.
__global__ __launch_bounds__(256, 4) void enc_kernel(
    const float* __restrict__ feat, const unsigned short* __restrict__ wt,
    const float* __restrict__ outc, float* __restrict__ part){
  __shared__ __align__(16) unsigned short cl0[MKB*KSTR];
  __shared__ __align__(16) unsigned short cl1[MKB*KSTR];
  __shared__ float2 wxs[TAPN]; __shared__ int2 xos[TAPN];
  __shared__ float2 wys[TAPN]; __shared__ int2 yos[TAPN];
  __shared__ float rAx[MKB], rSx[MKB], rAy[MKB], rSy[MKB];
  const int tid = threadIdx.x;
  const int fs  = blockIdx.x % FSPLIT;
  const int kb0 = (blockIdx.x / FSPLIT) * MKB;
  if (tid < MKB){
    float bx = outc[OFF_BXF + kb0 + tid];
    float by = outc[OFF_BYF + kb0 + tid];
    float bw = outc[OFF_BWF + kb0 + tid];
    float bh = outc[OFF_BHF + kb0 + tid];
    float sx = bw * (1.0f/(float)CR), sy = bh * (1.0f/(float)CR);
    rSx[tid] = sx; rSy[tid] = sy;
    rAx[tid] = bx - 0.5f*bw + 0.5f*sx - 0.5f;
    rAy[tid] = by - 0.5f*bh + 0.5f*sy - 0.5f;
  }
  __syncthreads();
  #pragma unroll
  for (int it = 0; it < 4; it++){
    int idx = it*256 + tid;
    if (idx < 2*TAPN){
      int isy = idx >= TAPN;
      int q = idx - (isy ? TAPN : 0);
      int rr = q / 28, i = q - rr*28;
      float A = isy ? rAy[rr] : rAx[rr];
      float S = isy ? rSy[rr] : rSx[rr];
      float x = fmaf((float)i, S, A);
      float x0f = floorf(x); int x0 = (int)x0f;
      float w1 = x - x0f, w0 = 1.0f - w1;
      if ((unsigned)x0     >= WRAW) w0 = 0.f;
      if ((unsigned)(x0+1) >= WRAW) w1 = 0.f;
      int c0 = min(max(x0,0),WRAW-1), c1 = min(max(x0+1,0),WRAW-1);
      if (isy){ wys[q] = make_float2(w0,w1); yos[q] = make_int2(c0, c1); }
      else    { wxs[q] = make_float2(w0,w1); xos[q] = make_int2(c0*HRAW, c1*HRAW); }
    }
  }
  __syncthreads();
  float raw[8][4];
  int ji[8];
  const int fblk = fs*FPB;
  #define GATHER(CH) { \
    _Pragma("unroll") \
    for (int u = 0; u < 8; u++){ \
      int idx = u*256 + tid; \
      int rr = idx >> 7, ff = idx & 127; \
      int f = fblk + (CH)*CHK + ff; \
      int c = f / CR2; int p = f - c*CR2; \
      int i = p / CR;  int j = p - i*CR; \
      int ii = rr*28 + i, jj = rr*28 + j; \
      ji[u] = (jj << 16) | ii; \
      int2 xo = xos[ii]; int2 yo = yos[jj]; \
      const float* img = feat + (size_t)((rr & (B-1))*CFEAT + c)*(WRAW*HRAW); \
      raw[u][0] = img[xo.x + yo.x]; \
      raw[u][1] = img[xo.x + yo.y]; \
      raw[u][2] = img[xo.y + yo.x]; \
      raw[u][3] = img[xo.y + yo.y]; \
    } }
  #define STORE(DST) { \
    _Pragma("unroll") \
    for (int u = 0; u < 8; u++){ \
      int idx = u*256 + tid; \
      int rr = idx >> 7, ff = idx & 127; \
      int ii = ji[u] & 0xffff, jj = ji[u] >> 16; \
      float2 wx = wxs[ii]; float2 wy = wys[jj]; \
      float v = (raw[u][0]*wy.x + raw[u][1]*wy.y)*wx.x \
              + (raw[u][2]*wy.x + raw[u][3]*wy.y)*wx.y; \
      (DST)[rr*KSTR + ff] = f2bf(v); \
    } }
  GATHER(0);
  STORE(cl0);
  __syncthreads();
  const int lane = tid & 63, wv = tid >> 6;
  const int lr = lane & 15, lg = lane >> 4;
  f32x4 acc = {0.f,0.f,0.f,0.f};
  #pragma unroll
  for (int ch = 0; ch < NCH; ch++){
    unsigned short* cur = (ch & 1) ? cl1 : cl0;
    unsigned short* nxt = (ch & 1) ? cl0 : cl1;
    const unsigned short* bptr = wt + (size_t)(fs*16 + ch*4)*2048 + wv*512 + lane*8;
    bfrag b0 = *(const bfrag*)(bptr);
    bfrag b1 = *(const bfrag*)(bptr + 2048);
    bfrag b2 = *(const bfrag*)(bptr + 4096);
    bfrag b3 = *(const bfrag*)(bptr + 6144);
    if (ch < NCH-1){ GATHER(ch+1); }           // gathers stay in flight under MFMA
    const unsigned short* arow = &cur[lr*KSTR + lg*8];
    bfrag a0 = *(const bfrag*)(arow);
    bfrag a1 = *(const bfrag*)(arow + 32);
    bfrag a2 = *(const bfrag*)(arow + 64);
    bfrag a3 = *(const bfrag*)(arow + 96);
    acc = __builtin_amdgcn_mfma_f32_16x16x32_bf16(a0, b0, acc, 0, 0, 0);
    acc = __builtin_amdgcn_mfma_f32_16x16x32_bf16(a1, b1, acc, 0, 0, 0);
    acc = __builtin_amdgcn_mfma_f32_16x16x32_bf16(a2, b2, acc, 0, 0, 0);
    acc = __builtin_amdgcn_mfma_f32_16x16x32_bf16(a3, b3, acc, 0, 0, 0);
    if (ch < NCH-1){ STORE(nxt); }
    __syncthreads();
  }
  float* dst = part + ((size_t)fs*KB + kb0)*64;
  #pragma unroll
  for (int r = 0; r < 4; r++){
    int row = lg*4 + r;
    dst[row*64 + wv*16 + lr] = acc[r];
  }
  #undef GATHER
  #undef STORE
}

// K3: reduce enc partials (49 slices) + bias -> zi reparam/KL -> dec GEMM + act -> ws_small
__global__ __launch_bounds__(256) void zi_dec_kernel(
    const float* __restrict__ part, const float* __restrict__ benc,
    const float* __restrict__ ieps, const float* __restrict__ wdec,
    const float* __restrict__ bdec, float* __restrict__ out,
    float* __restrict__ ws){
  int kb = blockIdx.x;
  int d = threadIdx.x & 63, seg = threadIdx.x >> 6;
  float s0=0.f, s1=0.f;
  for (int f = seg; f < FSPLIT; f += 8)
    s0 += part[((size_t)f*KB + kb)*64 + d];
  for (int f = seg+4; f < FSPLIT; f += 8)
    s1 += part[((size_t)f*KB + kb)*64 + d];
  __shared__ float red[4][64];
  __shared__ float zs[ZID];
  __shared__ float cf_s;
  red[seg][d] = s0 + s1;
  __syncthreads();
  if (threadIdx.x < ZID){
    int dd = threadIdx.x;
    float mu = benc[dd]     + red[0][dd]     + red[1][dd]     + red[2][dd]     + red[3][dd];
    float pe = benc[ZID+dd] + red[0][ZID+dd] + red[1][ZID+dd] + red[2][ZID+dd] + red[3][ZID+dd];
    float sd = softpl(pe) + 1e-4f;
    float zsv = mu + sd*ieps[kb*ZID + dd];
    out[OFF_ZIS + kb*ZID + dd] = zsv;
    out[OFF_ZIK + kb*ZID + dd] = 0.5f*(mu*mu + sd*sd) - logf(sd) - 0.5f;
    zs[dd] = zsv;
  }
  if (threadIdx.x == 0) cf_s = out[OFF_CFEW + kb];
  __syncthreads();
  float cf = cf_s;
  for (int f = threadIdx.x; f < 2*CR2; f += 256){
    float a = bdec[f];
    #pragma unroll
    for (int q = 0; q < 8; q++){
      float4 w4 = *(const float4*)&wdec[f*ZID + q*4];
      a = fmaf(zs[q*4+0], w4.x, a);
      a = fmaf(zs[q*4+1], w4.y, a);
      a = fmaf(zs[q*4+2], w4.z, a);
      a = fmaf(zs[q*4+3], w4.w, a);
    }
    float v = (f < CR2) ? softpl(a) : sigm(a);
    ws[WS_SMALL + (size_t)kb*(2*CR2) + f] = v*cf;
  }
}

// K4 (v13): fused uncrop + compose with wave-uniform X-range skip.
__global__ __launch_bounds__(256) void uncrop_compose_kernel(
    const float* __restrict__ ws, float* __restrict__ out){
  const int t = blockIdx.x*256 + threadIdx.x;
  const int b = t >> 14, p = t & 16383;
  const int X = p >> 7, Y = p & 127;
  __shared__ float sAx[KOBJ], sSx[KOBJ], sAy[KOBJ], sSy[KOBJ];
  if (threadIdx.x < KOBJ){
    int k = threadIdx.x;
    float bx = out[OFF_BXF + k*B + b], bw = out[OFF_BWF + k*B + b];
    float by = out[OFF_BYF + k*B + b], bh = out[OFF_BHF + k*B + b];
    float ix = __fdividef((float)CR, bw), iy = __fdividef((float)CR, bh);
    sSx[k] = ix; sAx[k] = (0.5f*bw - bx)*ix - 0.5f;
    sSy[k] = iy; sAy[k] = (0.5f*bh - by)*iy - 0.5f;
  }
  __syncthreads();
  const float xc = (float)X + 0.5f, yc = (float)Y + 0.5f;
  float wr[KOBJ];
  float vi[KOBJ];
  float sum = 0.f;
  #pragma unroll
  for (int k = 0; k < KOBJ; k++){
    float x = fmaf(xc, sSx[k], sAx[k]);     // wave-uniform (X uniform per wave)
    float v0 = 0.f, v1 = 0.f;
    if (x > -1.0f && x < (float)CR){        // whole-wave skip when box row-range misses X
      float y = fmaf(yc, sSy[k], sAy[k]);
      const float* sm = ws + WS_SMALL + (size_t)(k*B + b)*(2*CR2);
      float x0f = floorf(x), y0f = floorf(y);
      int x0 = (int)x0f, y0 = (int)y0f;
      float wx1 = x - x0f, wx0 = 1.0f - wx1;
      float wy1 = y - y0f, wy0 = 1.0f - wy1;
      if ((unsigned)x0     >= CR) wx0 = 0.f;
      if ((unsigned)(x0+1) >= CR) wx1 = 0.f;
      if ((unsigned)y0     >= CR) wy0 = 0.f;
      if ((unsigned)(y0+1) >= CR) wy1 = 0.f;
      int x0c = min(max(x0,0),CR-1), x1c = min(max(x0+1,0),CR-1);
      int y0c = min(max(y0,0),CR-1), y1c = min(max(y0+1,0),CR-1);
      const float* r0 = sm + x0c*CR;
      const float* r1 = sm + x1c*CR;
      v0 = (r0[y0c]*wy0 + r0[y1c]*wy1)*wx0 + (r1[y0c]*wy0 + r1[y1c]*wy1)*wx1;
      const float* q0 = r0 + CR2;
      const float* q1 = r1 + CR2;
      v1 = (q0[y0c]*wy0 + q0[y1c]*wy1)*wx0 + (q1[y0c]*wy0 + q1[y1c]*wy1)*wx1;
    }
    wr[k] = v0; vi[k] = v1; sum += v0;
  }
  #pragma unroll
  for (int k = 0; k < KOBJ; k++)
    out[OFF_BIMG + (size_t)(k*B + b)*16384 + p] = vi[k];
  float th = ftanh(sum);
  float inv = 1.0f / fmaxf(sum, 1e-6f);
  #pragma unroll
  for (int k = 0; k < KOBJ; k++){
    size_t o = (size_t)(k*B + b)*16384 + p;
    out[OFF_BMASK  + o] = th * (wr[k] * inv);
    out[OFF_BMASKN + o] = (wr[k] == 0.f) ? 0.f : ftanh(wr[k]);
  }
}

extern "C" void kernel_launch(void* const* d_in, const int* in_sizes, int n_in,
                              void* d_out, int out_size, void* d_ws, size_t ws_size,
                              hipStream_t stream) {
  (void)in_sizes; (void)n_in; (void)out_size; (void)ws_size;
  const float* logit = (const float*)d_in[0];
  const float* zmu   = (const float*)d_in[1];
  const float* zstd  = (const float*)d_in[2];
  const float* zeps  = (const float*)d_in[3];
  const float* ieps  = (const float*)d_in[4];
  const float* feat  = (const float*)d_in[5];
  const float* wz    = (const float*)d_in[6];
  const float* bz    = (const float*)d_in[7];
  const float* wenc  = (const float*)d_in[8];
  const float* benc  = (const float*)d_in[9];
  const float* wdec  = (const float*)d_in[10];
  const float* bdec  = (const float*)d_in[11];
  float* out = (float*)d_out;
  float* ws  = (float*)d_ws;
  float* scr = out + OFF_BMASK;                 // scratch inside big_mask region, overwritten later
  float* part = scr + SCR_PART;                 // 1.2M floats
  unsigned short* wt = (unsigned short*)(scr + SCR_WT);  // 1.6M bf16, k-step fragments

  prep_kernel         <<<784 + B*4, 256, 0, stream>>>(wenc, wt, logit, zmu, zstd, zeps, wz, bz, out);
  enc_kernel          <<<(KB/MKB)*FSPLIT, 256, 0, stream>>>(feat, wt, out, part);
  zi_dec_kernel       <<<KB, 256, 0, stream>>>(part, benc, ieps, wdec, bdec, out, ws);
  uncrop_compose_kernel<<<(B*WRAW*HRAW)/256, 256, 0, stream>>>(ws, out);
}